// Round 4
// baseline (106.957 us; speedup 1.0000x reference)
//
#include <hip/hip_runtime.h>
#include <hip/hip_bf16.h>

// GaussianSmoothing (2,1,192,192,192) f32, separable K=13 sigma=2.
// Pass A blur_wh: fused W+H, LDS-FREE. Column-march along y with 13 rolling
//   float4 H-accumulators; W-blur computed on the fly from 5 overlapping
//   aligned float4 loads (L1-local). x -> d_ws
// Pass B col_blur: D-axis blur, rolling float4 accumulators. d_ws -> d_out

#define DIM 192
#define DIM2 (192 * 192)
#define NIMG 2
#define TOTAL (NIMG * DIM * DIM2)   // 14,155,776 floats

#define GTAPS                                                     \
    constexpr float G[13] = {                                     \
        2.2159242e-03f, 8.7641505e-03f, 2.6995483e-02f,           \
        6.4758800e-02f, 1.2098536e-01f, 1.7603266e-01f,           \
        1.9947114e-01f, 1.7603266e-01f, 1.2098536e-01f,           \
        6.4758800e-02f, 2.6995483e-02f, 8.7641505e-03f,           \
        2.2159242e-03f };

// ---------------------------------------------------------------------------
// Pass A: fused W+H. Column = (plane, xq): 2*192 planes x 48 quads = 18432
// columns; 6 y-chunks of 32 outputs (44 steps incl. 12-halo). Per step:
//   - load 5 aligned f4s (quads xq-2..xq+2, row i) -> 20-float window
//     (quad-granular validity == float validity since 192 = 48 quads exactly)
//   - W-blur: 4 outputs x 13 taps
//   - update 13 rolling H-accumulators; emit acc[0] when s >= 12
// No LDS. All loads/stores lane-consecutive f4 -> coalesced.
// Grid = 18432*6/256 = 432 blocks.
// ---------------------------------------------------------------------------
__global__ __launch_bounds__(256) void blur_wh(const float4* __restrict__ in,
                                               float4* __restrict__ out) {
    GTAPS
    const int gt = blockIdx.x * 256 + threadIdx.x;
    const int chunk = gt / 18432;        // uniform per block (18432 % 256 == 0)
    const int c = gt % 18432;
    const int plane = c / 48;
    const int xq = c % 48;
    const int base = plane * 9216 + xq;  // f4 units
    const int y0 = chunk * 32;

    float4 acc[13];
#pragma unroll
    for (int j = 0; j < 13; ++j) acc[j] = make_float4(0.f, 0.f, 0.f, 0.f);

#pragma unroll
    for (int s = 0; s < 44; ++s) {
        const int i = y0 - 6 + s;        // input row along y
        const bool yok = (i >= 0 && i < DIM);
        float f[20];
#pragma unroll
        for (int d = -2; d <= 2; ++d) {
            float4 v = make_float4(0.f, 0.f, 0.f, 0.f);
            if (yok && (unsigned)(xq + d) < 48u) v = in[base + i * 48 + d];
            *(float4*)&f[(d + 2) * 4] = v;
        }
        // W-blur this row's quad: f[m] = raw[x0 - 8 + m]
        float4 w;
        float* wp = &w.x;
#pragma unroll
        for (int j = 0; j < 4; ++j) {
            float a = 0.0f;
#pragma unroll
            for (int k = 0; k < 13; ++k) a += G[k] * f[j + k + 2];
            wp[j] = a;
        }
        // rolling H accumulation: acc[j] holds output row (i-6)+j, tap 12-j
#pragma unroll
        for (int j = 0; j < 13; ++j) {
            const float g = G[12 - j];
            acc[j].x += g * w.x;
            acc[j].y += g * w.y;
            acc[j].z += g * w.z;
            acc[j].w += g * w.w;
        }
        if (s >= 12) out[base + (i - 6) * 48] = acc[0];  // compile-time predicate
#pragma unroll
        for (int j = 0; j < 12; ++j) acc[j] = acc[j + 1];
        acc[12] = make_float4(0.f, 0.f, 0.f, 0.f);
    }
}

// ---------------------------------------------------------------------------
// Pass B: blur along D. Each thread owns a float4 column, marches 32 outputs
// (+12 halo) with 13 rolling float4 accumulators (fully unrolled).
//   D pass: Q=9216 (quads/plane), M=1769472 (image, f4), S=9216 (plane, f4)
// ncols = 18432; chunks = 6; block = 128 -> grid = 864.
// ---------------------------------------------------------------------------
template <int Q, int M, int S>
__global__ __launch_bounds__(128) void col_blur(const float4* __restrict__ in,
                                                float4* __restrict__ out) {
    GTAPS
    const int gt = blockIdx.x * 128 + threadIdx.x;
    const int chunk = gt / 18432;          // uniform per block (18432 % 128 == 0)
    const int c = gt % 18432;
    const int base = (c / Q) * M + (c % Q);
    const int d0 = chunk * 32;

    float4 acc[13];
#pragma unroll
    for (int j = 0; j < 13; ++j) acc[j] = make_float4(0.f, 0.f, 0.f, 0.f);

#pragma unroll
    for (int s = 0; s < 44; ++s) {
        const int i = d0 - 6 + s;
        float4 v = make_float4(0.f, 0.f, 0.f, 0.f);
        if (i >= 0 && i < DIM) v = in[base + i * S];
#pragma unroll
        for (int j = 0; j < 13; ++j) {
            const float g = G[12 - j];
            acc[j].x += g * v.x;
            acc[j].y += g * v.y;
            acc[j].z += g * v.z;
            acc[j].w += g * v.w;
        }
        if (s >= 12) out[base + (i - 6) * S] = acc[0];
#pragma unroll
        for (int j = 0; j < 12; ++j) acc[j] = acc[j + 1];
        acc[12] = make_float4(0.f, 0.f, 0.f, 0.f);
    }
}

extern "C" void kernel_launch(void* const* d_in, const int* in_sizes, int n_in,
                              void* d_out, int out_size, void* d_ws, size_t ws_size,
                              hipStream_t stream) {
    const float* x = (const float*)d_in[0];
    float* out = (float*)d_out;
    float* tmp = (float*)d_ws;  // 56.6 MB scratch

    // Pass A: fused W+H (no LDS), x -> tmp
    blur_wh<<<432, 256, 0, stream>>>((const float4*)x, (float4*)tmp);
    // Pass B: D axis (stride 36864 floats = 9216 f4), tmp -> out
    col_blur<9216, 1769472, 9216><<<864, 128, 0, stream>>>((const float4*)tmp, (float4*)out);
}

// Round 5
// 64.494 us; speedup vs baseline: 1.6584x; 1.6584x over previous
//
#include <hip/hip_runtime.h>
#include <hip/hip_bf16.h>

// GaussianSmoothing (2,1,192,192,192) f32, separable K=13 sigma=2.
// Pass A blur_wh: fused W+H, LDS-free, branch-free clamped loads + mask mults,
//   column-march along y (chunk=16) with 13 rolling float4 H-accumulators.
//   x -> d_ws
// Pass B col_blur: D-axis blur, rolling float4 accumulators. d_ws -> d_out

#define DIM 192
#define DIM2 (192 * 192)
#define NIMG 2
#define TOTAL (NIMG * DIM * DIM2)   // 14,155,776 floats

#define GTAPS                                                     \
    constexpr float G[13] = {                                     \
        2.2159242e-03f, 8.7641505e-03f, 2.6995483e-02f,           \
        6.4758800e-02f, 1.2098536e-01f, 1.7603266e-01f,           \
        1.9947114e-01f, 1.7603266e-01f, 1.2098536e-01f,           \
        6.4758800e-02f, 2.6995483e-02f, 8.7641505e-03f,           \
        2.2159242e-03f };

// ---------------------------------------------------------------------------
// Pass A: fused W+H. Column = (plane, xq): 384 planes x 48 quads = 18432
// columns; 12 y-chunks of 16 outputs (28 steps incl. 12-row halo).
// Per step, per lane:
//   - 5 aligned f4 loads, indices CLAMPED in row/quad so always in-bounds,
//     invalid quads zeroed by precomputed per-lane 0/1 multipliers (no branches
//     -> compiler is free to pipeline loads across steps)
//   - W-blur: 4 outputs x 13 taps; result scaled by y-validity mask
//   - 13 rolling H-accumulators; emit acc[0] when s >= 12 (compile-time)
// Grid = 18432*12/256 = 864 blocks x 256.
// ---------------------------------------------------------------------------
#define CH 16
#define NCHUNK 12

__global__ __launch_bounds__(256) void blur_wh(const float4* __restrict__ in,
                                               float4* __restrict__ out) {
    GTAPS
    const int gt = blockIdx.x * 256 + threadIdx.x;
    const int chunk = gt / 18432;        // uniform per block (18432 % 256 == 0)
    const int c = gt % 18432;
    const int plane = c / 48;
    const int xq = c % 48;
    const int base = plane * 9216;       // f4 units
    const int y0 = chunk * CH;

    // per-lane x-window masks and clamped quad offsets (hoisted out of loop)
    float xm[5];
    int qc[5];
#pragma unroll
    for (int d = 0; d < 5; ++d) {
        int q = xq + d - 2;
        xm[d] = (q >= 0 && q < 48) ? 1.0f : 0.0f;
        qc[d] = min(max(q, 0), 47);
    }

    float4 acc[13];
#pragma unroll
    for (int j = 0; j < 13; ++j) acc[j] = make_float4(0.f, 0.f, 0.f, 0.f);

#pragma unroll
    for (int s = 0; s < CH + 12; ++s) {
        const int i = y0 - 6 + s;                      // input row along y
        const float ym = (i >= 0 && i < DIM) ? 1.0f : 0.0f;
        const int ic = min(max(i, 0), DIM - 1);
        const float4* __restrict__ row = in + base + ic * 48;

        float f[20];
#pragma unroll
        for (int d = 0; d < 5; ++d) {
            float4 v = row[qc[d]];                     // always in-bounds
            if (d != 2) {                              // own quad always valid
                v.x *= xm[d]; v.y *= xm[d]; v.z *= xm[d]; v.w *= xm[d];
            }
            *(float4*)&f[d * 4] = v;
        }

        // W-blur this row's quad: f[m] = raw[4*xq - 8 + m] (masked)
        float4 w;
        float* wp = &w.x;
#pragma unroll
        for (int j = 0; j < 4; ++j) {
            float a = 0.0f;
#pragma unroll
            for (int k = 0; k < 13; ++k) a += G[k] * f[j + k + 2];
            wp[j] = a * ym;                            // y-validity folded here
        }

        // rolling H accumulation: acc[j] holds output row (i-6)+j, tap 12-j
#pragma unroll
        for (int j = 0; j < 13; ++j) {
            const float g = G[12 - j];
            acc[j].x += g * w.x;
            acc[j].y += g * w.y;
            acc[j].z += g * w.z;
            acc[j].w += g * w.w;
        }
        if (s >= 12) out[base + (y0 + s - 12) * 48 + xq] = acc[0];
#pragma unroll
        for (int j = 0; j < 12; ++j) acc[j] = acc[j + 1];
        acc[12] = make_float4(0.f, 0.f, 0.f, 0.f);
    }
}

// ---------------------------------------------------------------------------
// Pass B: blur along D. Each thread owns a float4 column, marches 32 outputs
// (+12 halo) with 13 rolling float4 accumulators (fully unrolled).
//   D pass: Q=9216 (quads/plane), M=1769472 (image, f4), S=9216 (plane, f4)
// ncols = 18432; chunks = 6; block = 128 -> grid = 864.
// ---------------------------------------------------------------------------
template <int Q, int M, int S>
__global__ __launch_bounds__(128) void col_blur(const float4* __restrict__ in,
                                                float4* __restrict__ out) {
    GTAPS
    const int gt = blockIdx.x * 128 + threadIdx.x;
    const int chunk = gt / 18432;          // uniform per block (18432 % 128 == 0)
    const int c = gt % 18432;
    const int base = (c / Q) * M + (c % Q);
    const int d0 = chunk * 32;

    float4 acc[13];
#pragma unroll
    for (int j = 0; j < 13; ++j) acc[j] = make_float4(0.f, 0.f, 0.f, 0.f);

#pragma unroll
    for (int s = 0; s < 44; ++s) {
        const int i = d0 - 6 + s;
        float4 v = make_float4(0.f, 0.f, 0.f, 0.f);
        if (i >= 0 && i < DIM) v = in[base + i * S];
#pragma unroll
        for (int j = 0; j < 13; ++j) {
            const float g = G[12 - j];
            acc[j].x += g * v.x;
            acc[j].y += g * v.y;
            acc[j].z += g * v.z;
            acc[j].w += g * v.w;
        }
        if (s >= 12) out[base + (i - 6) * S] = acc[0];
#pragma unroll
        for (int j = 0; j < 12; ++j) acc[j] = acc[j + 1];
        acc[12] = make_float4(0.f, 0.f, 0.f, 0.f);
    }
}

extern "C" void kernel_launch(void* const* d_in, const int* in_sizes, int n_in,
                              void* d_out, int out_size, void* d_ws, size_t ws_size,
                              hipStream_t stream) {
    const float* x = (const float*)d_in[0];
    float* out = (float*)d_out;
    float* tmp = (float*)d_ws;  // 56.6 MB scratch

    // Pass A: fused W+H (no LDS, branch-free loads), x -> tmp
    blur_wh<<<864, 256, 0, stream>>>((const float4*)x, (float4*)tmp);
    // Pass B: D axis (stride 36864 floats = 9216 f4), tmp -> out
    col_blur<9216, 1769472, 9216><<<864, 128, 0, stream>>>((const float4*)tmp, (float4*)out);
}